// Round 1
// baseline (466.012 us; speedup 1.0000x reference)
//
#include <hip/hip_runtime.h>
#include <hip/hip_fp16.h>

// Deep-BSDE fused forward.
// Key identity: y = y0 + sum_t [ DT*LAM*sum_d z_t^2 + sum_d z_t*dw_t ] -- no true
// sequential dependence, so all (b,t) rows are processed as one big 3-layer MLP.
//
// Shapes: dw,x [8192][100][50] f32; W1 [101][110]; W2 [110][110]; W3 [110][100]; y0 [1].
// Out: y [8192] f32.

#define DIMX 100
#define TS   50
#define TPAD 64
#define HID  110
#define K1   101
#define KA   120      // LDS row stride (f16 elems); 240 B, 16B-aligned frag reads
#define NB   2        // b-panels per group
#define MROWS 128     // NB * TPAD
#define DTCO 0.02f

typedef _Float16 f16;
typedef _Float16 f16x8 __attribute__((ext_vector_type(8)));
typedef float    f32x16 __attribute__((ext_vector_type(16)));

// Weight LDS row map (transposed storage Wt[n][k], row stride KA):
//   W1t rows [0,110)   : spill-reads (n up to 127) land in W3t region -> finite garbage, masked
//   W3t rows [110,210) : spill lands in W2t region
//   W2t rows [210,320) : spill lands in tail pad [320,338)
#define W1ROW 0
#define W3ROW 110
#define W2ROW 210
#define WROWS 338

__device__ __forceinline__ void mlp_layer(const f16* __restrict__ A,
                                          const f16* __restrict__ Wt,
                                          int m, int nh, int ln, int hi,
                                          f32x16& acc0, f32x16& acc1)
{
    const int arow = m * 32 + ln;
#pragma unroll
    for (int ks = 0; ks < 7; ++ks) {
        const f16x8 a   = *(const f16x8*)(A  + arow * KA            + ks * 16 + hi * 8);
        const f16x8 bv0 = *(const f16x8*)(Wt + (64 * nh      + ln) * KA + ks * 16 + hi * 8);
        const f16x8 bv1 = *(const f16x8*)(Wt + (64 * nh + 32 + ln) * KA + ks * 16 + hi * 8);
        acc0 = __builtin_amdgcn_mfma_f32_32x32x16_f16(a, bv0, acc0, 0, 0, 0);
        acc1 = __builtin_amdgcn_mfma_f32_32x32x16_f16(a, bv1, acc1, 0, 0, 0);
    }
}

__device__ __forceinline__ void store_h(f16* __restrict__ H, const f32x16& acc0,
                                        const f32x16& acc1, int m, int nh, int ln, int hi)
{
#pragma unroll
    for (int j = 0; j < 2; ++j) {
        const int col = 64 * nh + 32 * j + ln;
        if (col < HID) {
#pragma unroll
            for (int q = 0; q < 16; ++q) {
                const int row = 32 * m + (q & 3) + 8 * (q >> 2) + 4 * hi;
                float v = j ? acc1[q] : acc0[q];
                v = v > 0.f ? v : 0.f;              // relu
                H[row * KA + col] = (f16)v;
            }
        } else if (col < 112) {                      // k=110,111 are read by k-steps: zero them
#pragma unroll
            for (int q = 0; q < 16; ++q) {
                const int row = 32 * m + (q & 3) + 8 * (q >> 2) + 4 * hi;
                H[row * KA + col] = (f16)0.f;
            }
        } // col >= 112: never read as fragments, skip
    }
}

__launch_bounds__(512, 2)
__global__ void bsde_kernel(const float* __restrict__ dw, const float* __restrict__ x,
                            const float* __restrict__ W1, const float* __restrict__ W2,
                            const float* __restrict__ W3, const float* __restrict__ y0,
                            float* __restrict__ out)
{
    __shared__ __align__(16) f16 wlds[WROWS * KA];
    __shared__ __align__(16) f16 buf0[MROWS * KA];   // A1 / h2 ping
    __shared__ __align__(16) f16 buf1[MROWS * KA];   // h1 pong
    __shared__ float yacc[MROWS];

    const int tid  = threadIdx.x;
    const int lane = tid & 63;
    const int w    = tid >> 6;    // wave 0..7
    const int ln   = lane & 31;
    const int hi   = lane >> 5;
    const int m    = w >> 1;      // M-tile 0..3 (32 rows each)
    const int nh   = w & 1;       // N-half: cols 64*nh .. 64*nh+63

    // ---------------- weight prepass (once per block) ----------------
    for (int i = tid; i < WROWS * KA; i += 512) wlds[i] = (f16)0.f;  // zero incl. K-pad
    __syncthreads();
    for (int e = tid; e < K1 * HID; e += 512) {
        const int k = e / HID, n = e % HID;
        wlds[(W1ROW + n) * KA + k] = (f16)W1[e];
    }
    for (int e = tid; e < HID * HID; e += 512) {
        const int k = e / HID, n = e % HID;
        wlds[(W2ROW + n) * KA + k] = (f16)W2[e];
    }
    for (int e = tid; e < HID * DIMX; e += 512) {
        const int k = e / DIMX, n = e % DIMX;
        wlds[(W3ROW + n) * KA + k] = (f16)W3[e];
    }
    // zero A1 pad cols 101..111 once (stale LDS could be NaN; later groups leave finite h2)
    for (int i = tid; i < MROWS * 11; i += 512) {
        const int r = i / 11, c = 101 + i % 11;
        buf0[r * KA + c] = (f16)0.f;
    }
    __syncthreads();

    const int   b0base = blockIdx.x * 32;
    const float yinit  = y0[0];

    for (int g = 0; g < 16; ++g) {
        const int b0 = b0base + 2 * g;

        // ---------------- stage: A1 rows = (panel, t), k0 = t-value, k1..100 = x ----------------
        if (tid < MROWS) yacc[tid] = 0.f;
        if (tid >= MROWS && tid < 2 * MROWS) {
            const int r = tid - MROWS, t = r & 63;
            buf0[r * KA] = (t < TS) ? (f16)(t * DTCO) : (f16)0.f;
        }
        for (int tau = tid; tau < NB * DIMX * 25; tau += 512) {
            const int p   = tau / (DIMX * 25);
            const int rem = tau - p * DIMX * 25;
            const int d   = rem / 25;
            const int c2  = rem - d * 25;                    // t-pair 0..24 -> t = 2*c2, 2*c2+1
            const float2 v = *(const float2*)(x + ((size_t)(b0 + p) * DIMX + d) * TS + 2 * c2);
            const int r = p * TPAD + 2 * c2;
            buf0[r       * KA + 1 + d] = (f16)v.x;
            buf0[(r + 1) * KA + 1 + d] = (f16)v.y;
        }
        __syncthreads();

        // ---------------- layer 1: buf0 -> buf1 ----------------
        {
            f32x16 a0, a1;
#pragma unroll
            for (int i = 0; i < 16; ++i) { a0[i] = 0.f; a1[i] = 0.f; }
            mlp_layer(buf0, wlds + W1ROW * KA, m, nh, ln, hi, a0, a1);
            store_h(buf1, a0, a1, m, nh, ln, hi);
        }
        __syncthreads();

        // ---------------- layer 2: buf1 -> buf0 ----------------
        {
            f32x16 a0, a1;
#pragma unroll
            for (int i = 0; i < 16; ++i) { a0[i] = 0.f; a1[i] = 0.f; }
            mlp_layer(buf1, wlds + W2ROW * KA, m, nh, ln, hi, a0, a1);
            store_h(buf0, a0, a1, m, nh, ln, hi);
        }
        __syncthreads();

        // ---------------- layer 3 + z*dw + DT*z^2 ----------------
        {
            f32x16 a0, a1;
#pragma unroll
            for (int i = 0; i < 16; ++i) { a0[i] = 0.f; a1[i] = 0.f; }
            mlp_layer(buf0, wlds + W3ROW * KA, m, nh, ln, hi, a0, a1);

            float psum[16];
#pragma unroll
            for (int i = 0; i < 16; ++i) psum[i] = 0.f;

#pragma unroll
            for (int j = 0; j < 2; ++j) {
                const int d = 64 * nh + 32 * j + ln;
                if (d < DIMX) {
#pragma unroll
                    for (int qq = 0; qq < 4; ++qq) {
                        const int rbase = 32 * m + 8 * qq + 4 * hi;  // rows rbase..rbase+3
                        const int t0 = rbase & 63;
                        const int p  = rbase >> 6;
                        float dv[4];
                        const float* dwp = dw + ((size_t)(b0 + p) * DIMX + d) * TS + t0;
                        if (t0 < TS)     { const float2 u = *(const float2*)dwp;       dv[0] = u.x; dv[1] = u.y; }
                        else             { dv[0] = 0.f; dv[1] = 0.f; }
                        if (t0 + 2 < TS) { const float2 u = *(const float2*)(dwp + 2); dv[2] = u.x; dv[3] = u.y; }
                        else             { dv[2] = 0.f; dv[3] = 0.f; }
#pragma unroll
                        for (int i = 0; i < 4; ++i) {
                            if (t0 + i < TS) {   // branch-gate (not multiply): keeps NaN out
                                const float z = (j ? a1[qq * 4 + i] : a0[qq * 4 + i]) * (1.0f / DIMX);
                                psum[qq * 4 + i] += DTCO * z * z + z * dv[i];  // LAM = 1
                            }
                        }
                    }
                }
            }
            // reduce each row-slot across the 32-lane half (cols)
#pragma unroll
            for (int s = 0; s < 16; ++s) {
                float v = psum[s];
#pragma unroll
                for (int off = 1; off < 32; off <<= 1) v += __shfl_xor(v, off);
                psum[s] = v;
            }
            if (ln < 16) {
                float myv = 0.f;
#pragma unroll
                for (int s = 0; s < 16; ++s) if (ln == s) myv = psum[s];  // static index select
                const int row = 32 * m + (ln & 3) + 8 * (ln >> 2) + 4 * hi;
                if ((row & 63) < TS) atomicAdd(&yacc[row], myv);
            }
        }
        __syncthreads();

        // ---------------- y write: one wave per panel ----------------
        if (w < NB) {
            float v = (lane < TS) ? yacc[w * TPAD + lane] : 0.f;
#pragma unroll
            for (int off = 1; off < 64; off <<= 1) v += __shfl_xor(v, off);
            if (lane == 0) out[b0 + w] = yinit + v;
        }
        __syncthreads();
    }
}

extern "C" void kernel_launch(void* const* d_in, const int* in_sizes, int n_in,
                              void* d_out, int out_size, void* d_ws, size_t ws_size,
                              hipStream_t stream) {
    const float* dw = (const float*)d_in[0];
    const float* x  = (const float*)d_in[1];
    const float* W1 = (const float*)d_in[2];
    const float* W2 = (const float*)d_in[3];
    const float* W3 = (const float*)d_in[4];
    const float* y0 = (const float*)d_in[5];
    float* out = (float*)d_out;
    bsde_kernel<<<dim3(256), dim3(512), 0, stream>>>(dw, x, W1, W2, W3, y0, out);
}